// Round 4
// baseline (347.760 us; speedup 1.0000x reference)
//
#include <hip/hip_runtime.h>

#define BATCH   16384
#define NUM_NUM 32
#define NUM_CAT 32
#define CARD    128
#define OUT_F   32
#define XSTRIDE 4128   // NUM_NUM + NUM_CAT*CARD
#define OSTRIDE 1056   // NUM_NUM + NUM_CAT*OUT_F

#define TRB    512          // rows per block
#define CK     8            // K cols per chunk
#define NCHUNK (CARD / CK)  // 16
#define QPC    (TRB * CK / 4)  // 1024 float4 quads in x_s

// 256 threads = 4 waves. Wave wv owns outputs [wv*8, wv*8+8) (wave-uniform ->
// W comes via scalar s_load from L2, NOT the LDS pipe). Lane l owns rows l*8+j.
// x_s: single 16KB buffer, XOR-swizzled quads: phys P = Q ^ ((Q>>4)&7)
//   reads:  Q = l*16 + (j*2+sq)  -> (Q>>4)&7 = l&7   -> 2-way per 16-lane phase (free)
//   writes: Q = i*256 + tid      -> (Q>>4)&7 = (tid>>4)&7 -> 2-way (free)
// Staging: r1-proven register-held prefetch (4 float4/thread), 2 barriers/chunk.
// LDS pipe budget: (16 rd + 4 wr) b128/chunk/wave -> ~25us chip; VALU ~29us; HBM 54us floor.
__global__ __launch_bounds__(256, 4) void emb_gemm(const float* __restrict__ x,
                                                   const float* __restrict__ Wm,
                                                   const float* __restrict__ bias,
                                                   float* __restrict__ out) {
    __shared__ float4 x_s[QPC];  // 16 KB

    const int f    = blockIdx.y;
    const int row0 = blockIdx.x * TRB;
    const int tid  = threadIdx.x;
    const int l    = tid & 63;
    const int wog  = __builtin_amdgcn_readfirstlane(tid >> 6);  // wave's out-group, SGPR
    const int lx   = l & 7;            // read-side swizzle xor
    const int wxor = (tid >> 4) & 7;   // write-side swizzle xor

    // Wave-uniform W pointer: W[f][c][wog*8 .. +8) = wq[c*8], wq[c*8+1]
    const float4* wq = (const float4*)Wm + ((size_t)f * (CARD * OUT_F / 4) + wog * 2);

    const float* xg = x + (size_t)row0 * XSTRIDE + NUM_NUM + f * CARD;

    float acc[8][8];
#pragma unroll
    for (int j = 0; j < 8; ++j)
#pragma unroll
        for (int k = 0; k < 8; ++k) acc[j][k] = 0.0f;

    float4 st[4];
    // ---- prologue: stage chunk 0 ----
#pragma unroll
    for (int i = 0; i < 4; ++i) {
        int n = i * 256 + tid;           // logical quad: row n>>1, half n&1
        st[i] = *(const float4*)(xg + (size_t)(n >> 1) * XSTRIDE + (n & 1) * 4);
    }
#pragma unroll
    for (int i = 0; i < 4; ++i) x_s[(i * 256 + tid) ^ wxor] = st[i];
    __syncthreads();

    for (int ck = 0; ck < NCHUNK; ++ck) {
        // register-held prefetch of chunk ck+1 (lands during compute; consumed after barrier)
        if (ck + 1 < NCHUNK) {
            const float* xn = xg + (ck + 1) * CK;
#pragma unroll
            for (int i = 0; i < 4; ++i) {
                int n = i * 256 + tid;
                st[i] = *(const float4*)(xn + (size_t)(n >> 1) * XSTRIDE + (n & 1) * 4);
            }
        }

        // compute chunk ck: 2 quad-steps x 2 row-halves x (4 cc x 4 rows x 8 outs)
#pragma unroll
        for (int sq = 0; sq < 2; ++sq) {
#pragma unroll
            for (int jh = 0; jh < 8; jh += 4) {
                float4 xv[4];
#pragma unroll
                for (int jj = 0; jj < 4; ++jj)
                    xv[jj] = x_s[l * 16 + (((jh + jj) * 2 + sq) ^ lx)];
#pragma unroll
                for (int cc = 0; cc < 4; ++cc) {
                    const int    c  = ck * CK + sq * 4 + cc;
                    const float4 wa = wq[c * 8];      // scalar loads (uniform addr)
                    const float4 wb = wq[c * 8 + 1];
#pragma unroll
                    for (int jj = 0; jj < 4; ++jj) {
                        const float xf = (&xv[jj].x)[cc];
                        float* a = acc[jh + jj];
                        a[0] += xf * wa.x;  a[1] += xf * wa.y;
                        a[2] += xf * wa.z;  a[3] += xf * wa.w;
                        a[4] += xf * wb.x;  a[5] += xf * wb.y;
                        a[6] += xf * wb.z;  a[7] += xf * wb.w;
                    }
                }
            }
        }

        __syncthreads();  // all reads of chunk ck done (also drains st prefetch vmcnt)
        if (ck + 1 < NCHUNK) {
#pragma unroll
            for (int i = 0; i < 4; ++i) x_s[(i * 256 + tid) ^ wxor] = st[i];
        }
        __syncthreads();  // chunk ck+1 visible
    }

    // ---- epilogue: bias + 8 rows x 2 float4 ----
    const float4* bq = (const float4*)bias + (f * (OUT_F / 4) + wog * 2);
    const float4  ba = bq[0];
    const float4  bb = bq[1];
#pragma unroll
    for (int j = 0; j < 8; ++j) {
        size_t ob = (size_t)(row0 + l * 8 + j) * OSTRIDE + NUM_NUM + f * OUT_F + wog * 8;
        float4 o0, o1;
        o0.x = acc[j][0] + ba.x; o0.y = acc[j][1] + ba.y;
        o0.z = acc[j][2] + ba.z; o0.w = acc[j][3] + ba.w;
        o1.x = acc[j][4] + bb.x; o1.y = acc[j][5] + bb.y;
        o1.z = acc[j][6] + bb.z; o1.w = acc[j][7] + bb.w;
        *(float4*)(out + ob)     = o0;
        *(float4*)(out + ob + 4) = o1;
    }

    // ---- numeric passthrough, distributed: block (rb,f) copies rows [row0+f*16, +16) ----
    if (tid < 128) {
        int r  = row0 + f * 16 + (tid >> 3);
        int c4 = (tid & 7) << 2;
        *(float4*)(out + (size_t)r * OSTRIDE + c4) =
            *(const float4*)(x + (size_t)r * XSTRIDE + c4);
    }
}

extern "C" void kernel_launch(void* const* d_in, const int* in_sizes, int n_in,
                              void* d_out, int out_size, void* d_ws, size_t ws_size,
                              hipStream_t stream) {
    const float* x    = (const float*)d_in[0];
    const float* W    = (const float*)d_in[1];
    const float* bias = (const float*)d_in[2];
    float*       out  = (float*)d_out;

    dim3 grid(BATCH / TRB, NUM_CAT);  // 32 x 32 = 1024 blocks, all resident at 4/CU
    emb_gemm<<<grid, 256, 0, stream>>>(x, W, bias, out);
}

// Round 5
// 158.365 us; speedup vs baseline: 2.1959x; 2.1959x over previous
//
#include <hip/hip_runtime.h>

#define BATCH   16384
#define NUM_NUM 32
#define NUM_CAT 32
#define CARD    128
#define OUT_F   32
#define XSTRIDE 4128   // NUM_NUM + NUM_CAT*CARD
#define OSTRIDE 1056   // NUM_NUM + NUM_CAT*OUT_F

#define TRB    512             // rows per block
#define CK     8               // K cols per chunk
#define NCHUNK (CARD / CK)     // 16
#define QPC    (TRB * CK / 4)  // 1024 float4 quads per x buffer

typedef const __attribute__((address_space(1))) void* as1_cvp;
typedef __attribute__((address_space(3))) void*       as3_vp;

// 256 threads = 4 waves. Thread tile: 8 rows x 8 outs (og = tid&3, rg = tid>>2).
// x_s: XOR-swizzled quads, phys P = Q ^ ((Q>>4)&7) (involution).
//   read  (fixed j,sq): 16 distinct addrs sweep all 8 bank-quads 2x -> free (m136).
//   stage: global_load_lds width 16, LINEAR dest + inverse-swizzled SOURCE (rule 21).
// W[f] in LDS linear: reads are 16-lane broadcasts of 4 addrs on 4 distinct
//   bank-quads (c*8 + og*2 + k, og=0..3) -> conflict-free, no swizzle.
// Double-buffered staging, ONE barrier per chunk. No register-held prefetch -> no
// VGPR cliff (launch_bounds(256,1): allocator uncapped; LDS 48KB caps 3 blocks/CU).
__global__ __launch_bounds__(256, 1) void emb_gemm(const float* __restrict__ x,
                                                   const float* __restrict__ Wm,
                                                   const float* __restrict__ bias,
                                                   float* __restrict__ out) {
    __shared__ float4 w_s[CARD * OUT_F / 4];  // 16 KB, [c][o] quads, linear
    __shared__ float4 x_s[2][QPC];            // 2 x 16 KB, swizzled

    const int f    = blockIdx.y;
    const int row0 = blockIdx.x * TRB;
    const int tid  = threadIdx.x;
    const int og   = tid & 3;    // 4 out-groups of 8
    const int rg   = tid >> 2;   // 64 row-groups of 8
    const int rgx  = rg & 7;     // read-side swizzle xor

    // ---- stage W[f]: 1024 quads, async, linear both sides ----
    const float* wg = Wm + (size_t)f * (CARD * OUT_F);
#pragma unroll
    for (int i = 0; i < 4; ++i) {
        int n = i * 256 + tid;
        __builtin_amdgcn_global_load_lds((as1_cvp)(wg + n * 4), (as3_vp)&w_s[n], 16, 0, 0);
    }

    const float* xg = x + (size_t)row0 * XSTRIDE + NUM_NUM + f * CARD;

    // per-lane inverse-swizzled source offsets (chunk-independent)
    int soff[4];
#pragma unroll
    for (int i = 0; i < 4; ++i) {
        int P   = i * 256 + tid;
        int Q   = P ^ ((P >> 4) & 7);
        soff[i] = (Q >> 1) * XSTRIDE + (Q & 1) * 4;  // row = Q>>1, col-quad = Q&1
    }

    // prologue: stage chunk 0 -> buf 0
#pragma unroll
    for (int i = 0; i < 4; ++i)
        __builtin_amdgcn_global_load_lds((as1_cvp)(xg + soff[i]),
                                         (as3_vp)&x_s[0][i * 256 + tid], 16, 0, 0);
    __syncthreads();  // drains vmcnt: W + chunk 0 visible

    float acc[8][8];
#pragma unroll
    for (int j = 0; j < 8; ++j)
#pragma unroll
        for (int k = 0; k < 8; ++k) acc[j][k] = 0.0f;

    for (int ck = 0; ck < NCHUNK; ++ck) {
        // async-stage next chunk into the other buffer (lands during compute)
        if (ck + 1 < NCHUNK) {
            const float* xn  = xg + (ck + 1) * CK;
            float4*      dst = x_s[(ck + 1) & 1];
#pragma unroll
            for (int i = 0; i < 4; ++i)
                __builtin_amdgcn_global_load_lds((as1_cvp)(xn + soff[i]),
                                                 (as3_vp)&dst[i * 256 + tid], 16, 0, 0);
        }

        const float4* xb = x_s[ck & 1];
#pragma unroll
        for (int sq = 0; sq < 2; ++sq) {
            float4 xv[8];
#pragma unroll
            for (int j = 0; j < 8; ++j) {
                int Q = (rg * 8 + j) * 2 + sq;  // (Q>>4)&7 == rgx
                xv[j] = xb[Q ^ rgx];
            }
#pragma unroll
            for (int cc = 0; cc < 4; ++cc) {
                const int    c  = ck * CK + sq * 4 + cc;
                const float4 wa = w_s[c * 8 + og * 2];
                const float4 wb = w_s[c * 8 + og * 2 + 1];
#pragma unroll
                for (int j = 0; j < 8; ++j) {
                    const float xf = (&xv[j].x)[cc];
                    float*      a  = acc[j];
                    a[0] += xf * wa.x;  a[1] += xf * wa.y;
                    a[2] += xf * wa.z;  a[3] += xf * wa.w;
                    a[4] += xf * wb.x;  a[5] += xf * wb.y;
                    a[6] += xf * wb.z;  a[7] += xf * wb.w;
                }
            }
        }
        // one barrier per chunk: publishes staged chunk ck+1 (vmcnt drain) and
        // guarantees buf ck is free for the stage issued at top of iter ck+2.
        __syncthreads();
    }

    // ---- epilogue: bias + 8 rows x 2 float4; 4 lanes cover a row's 128B (coalesced) ----
    const float4* bq = (const float4*)bias + f * (OUT_F / 4);
    const float4  ba = bq[og * 2];
    const float4  bb = bq[og * 2 + 1];
#pragma unroll
    for (int j = 0; j < 8; ++j) {
        size_t ob = (size_t)(row0 + rg * 8 + j) * OSTRIDE + NUM_NUM + f * OUT_F + og * 8;
        float4 o0, o1;
        o0.x = acc[j][0] + ba.x; o0.y = acc[j][1] + ba.y;
        o0.z = acc[j][2] + ba.z; o0.w = acc[j][3] + ba.w;
        o1.x = acc[j][4] + bb.x; o1.y = acc[j][5] + bb.y;
        o1.z = acc[j][6] + bb.z; o1.w = acc[j][7] + bb.w;
        *(float4*)(out + ob)     = o0;
        *(float4*)(out + ob + 4) = o1;
    }

    // ---- numeric passthrough, distributed: block (rb,f) copies rows [row0+f*16, +16) ----
    if (tid < 128) {
        int r  = row0 + f * 16 + (tid >> 3);
        int c4 = (tid & 7) << 2;
        *(float4*)(out + (size_t)r * OSTRIDE + c4) =
            *(const float4*)(x + (size_t)r * XSTRIDE + c4);
    }
}

extern "C" void kernel_launch(void* const* d_in, const int* in_sizes, int n_in,
                              void* d_out, int out_size, void* d_ws, size_t ws_size,
                              hipStream_t stream) {
    const float* x    = (const float*)d_in[0];
    const float* W    = (const float*)d_in[1];
    const float* bias = (const float*)d_in[2];
    float*       out  = (float*)d_out;

    dim3 grid(BATCH / TRB, NUM_CAT);  // 32 x 32 = 1024 blocks
    emb_gemm<<<grid, 256, 0, stream>>>(x, W, bias, out);
}

// Round 6
// 123.080 us; speedup vs baseline: 2.8255x; 1.2867x over previous
//
#include <hip/hip_runtime.h>

#define BATCH   16384
#define NUM_NUM 32
#define NUM_CAT 32
#define CARD    128
#define OUT_F   32
#define XSTRIDE 4128   // NUM_NUM + NUM_CAT*CARD
#define OSTRIDE 1056   // NUM_NUM + NUM_CAT*OUT_F

#define TRB    512             // rows per block
#define CK     32              // K cols per chunk -> 128B contiguous per row per stage
#define NCHUNK (CARD / CK)     // 4
#define QPC    (TRB * CK / 4)  // 4096 float4 quads per x buffer (64 KB)

typedef const __attribute__((address_space(1))) void* as1_cvp;
typedef __attribute__((address_space(3))) void*       as3_vp;

// 256 threads = 4 waves. Thread tile: 8 rows x 8 outs (og = tid&3, rg = tid>>2).
// x_s: XOR-swizzled quads, phys P = Q ^ ((Q>>6)&7), Q = row*8 + colquad (involution;
//   the XOR bits 0..2 never touch bits >=6, so (Q>>6) == (P>>6)).
//   read (fixed j,sq): Q = rg*64 + j*8 + sq -> bank-quad sq^(rg&7): per wave 16 rg ->
//   8 bank-quads x 2 addrs x 4-lane og-broadcast == r5's measured-conflict-free pattern.
//   stage instr i, lane l: phys P = i*64+l holds Q = i*64 + (l^(i&7)) -> row i*8+(l>>3),
//   cq (l&7)^(i&7): each 8-lane group reads ONE row's 128B slice (permuted in-segment)
//   -> 128B DRAM granule (vs r5's 32B, which capped HBM at 2.1 TB/s).
// W[f] in LDS linear: 4 distinct quads x 16-lane broadcast -> conflict-free.
// LDS 16KB + 2x64KB = 144KB -> 1 block/CU; dbuf keeps 64KB permanently in flight.
__global__ __launch_bounds__(256, 1) void emb_gemm(const float* __restrict__ x,
                                                   const float* __restrict__ Wm,
                                                   const float* __restrict__ bias,
                                                   float* __restrict__ out) {
    __shared__ float4 w_s[CARD * OUT_F / 4];  // 16 KB, [c][o] quads, linear
    __shared__ float4 x_s[2][QPC];            // 2 x 64 KB, swizzled

    const int f    = blockIdx.y;
    const int row0 = blockIdx.x * TRB;
    const int tid  = threadIdx.x;
    const int l    = tid & 63;
    const int wv   = tid >> 6;
    const int og   = tid & 3;    // 4 out-groups of 8
    const int rg   = tid >> 2;   // 64 row-groups of 8
    const int rgx  = rg & 7;     // read-side swizzle xor

    // ---- stage W[f]: 1024 quads, async, linear both sides ----
    const float* wg = Wm + (size_t)f * (CARD * OUT_F);
#pragma unroll
    for (int i = 0; i < 4; ++i) {
        int n = i * 256 + tid;
        __builtin_amdgcn_global_load_lds((as1_cvp)(wg + n * 4), (as3_vp)&w_s[n], 16, 0, 0);
    }

    const float* xg = x + (size_t)row0 * XSTRIDE + NUM_NUM + f * CARD;

    // per-lane inverse-swizzled source offsets, chunk-independent.
    // instr i = wv*16+s covers phys quads [i*64, i*64+64): lane l supplies
    // row i*8+(l>>3), colquad (l&7)^(i&7)  (i&7 == s&7 since wv*16 % 8 == 0).
    int soff[16];
#pragma unroll
    for (int s = 0; s < 16; ++s) {
        int i   = wv * 16 + s;
        int row = i * 8 + (l >> 3);
        int cq  = (l & 7) ^ (i & 7);
        soff[s] = row * XSTRIDE + cq * 4;
    }

    // prologue: stage chunk 0 -> buf 0
#pragma unroll
    for (int s = 0; s < 16; ++s)
        __builtin_amdgcn_global_load_lds((as1_cvp)(xg + soff[s]),
                                         (as3_vp)&x_s[0][(wv * 16 + s) * 64 + l], 16, 0, 0);
    __syncthreads();  // drains vmcnt: W + chunk 0 visible

    float acc[8][8];
#pragma unroll
    for (int j = 0; j < 8; ++j)
#pragma unroll
        for (int k = 0; k < 8; ++k) acc[j][k] = 0.0f;

    for (int ck = 0; ck < NCHUNK; ++ck) {
        // async-stage next chunk into the other buffer (lands during compute)
        if (ck + 1 < NCHUNK) {
            const float* xn  = xg + (ck + 1) * CK;
            float4*      dst = x_s[(ck + 1) & 1];
#pragma unroll
            for (int s = 0; s < 16; ++s)
                __builtin_amdgcn_global_load_lds((as1_cvp)(xn + soff[s]),
                                                 (as3_vp)&dst[(wv * 16 + s) * 64 + l], 16, 0, 0);
        }

        const float4* xb = x_s[ck & 1];
#pragma unroll
        for (int sq = 0; sq < 8; ++sq) {   // 8 quad-steps of 4 cols
            float4 xv[8];
#pragma unroll
            for (int j = 0; j < 8; ++j) {
                int Q = (rg * 8 + j) * 8 + sq;  // (Q>>6)&7 == rgx
                xv[j] = xb[Q ^ rgx];
            }
#pragma unroll
            for (int cc = 0; cc < 4; ++cc) {
                const int    c  = ck * CK + sq * 4 + cc;
                const float4 wa = w_s[c * 8 + og * 2];
                const float4 wb = w_s[c * 8 + og * 2 + 1];
#pragma unroll
                for (int j = 0; j < 8; ++j) {
                    const float xf = (&xv[j].x)[cc];
                    float*      a  = acc[j];
                    a[0] += xf * wa.x;  a[1] += xf * wa.y;
                    a[2] += xf * wa.z;  a[3] += xf * wa.w;
                    a[4] += xf * wb.x;  a[5] += xf * wb.y;
                    a[6] += xf * wb.z;  a[7] += xf * wb.w;
                }
            }
        }
        // one barrier per chunk: publishes staged chunk ck+1 and frees buf ck.
        __syncthreads();
    }

    // ---- epilogue: bias + 8 rows x 2 float4; 4 lanes cover a row's 128B (coalesced) ----
    const float4* bq = (const float4*)bias + f * (OUT_F / 4);
    const float4  ba = bq[og * 2];
    const float4  bb = bq[og * 2 + 1];
#pragma unroll
    for (int j = 0; j < 8; ++j) {
        size_t ob = (size_t)(row0 + rg * 8 + j) * OSTRIDE + NUM_NUM + f * OUT_F + og * 8;
        float4 o0, o1;
        o0.x = acc[j][0] + ba.x; o0.y = acc[j][1] + ba.y;
        o0.z = acc[j][2] + ba.z; o0.w = acc[j][3] + ba.w;
        o1.x = acc[j][4] + bb.x; o1.y = acc[j][5] + bb.y;
        o1.z = acc[j][6] + bb.z; o1.w = acc[j][7] + bb.w;
        *(float4*)(out + ob)     = o0;
        *(float4*)(out + ob + 4) = o1;
    }

    // ---- numeric passthrough, distributed: block (rb,f) copies rows [row0+f*16, +16) ----
    if (tid < 128) {
        int r  = row0 + f * 16 + (tid >> 3);
        int c4 = (tid & 7) << 2;
        *(float4*)(out + (size_t)r * OSTRIDE + c4) =
            *(const float4*)(x + (size_t)r * XSTRIDE + c4);
    }
}

extern "C" void kernel_launch(void* const* d_in, const int* in_sizes, int n_in,
                              void* d_out, int out_size, void* d_ws, size_t ws_size,
                              hipStream_t stream) {
    const float* x    = (const float*)d_in[0];
    const float* W    = (const float*)d_in[1];
    const float* bias = (const float*)d_in[2];
    float*       out  = (float*)d_out;

    dim3 grid(BATCH / TRB, NUM_CAT);  // 32 x 32 = 1024 blocks, 4 rounds at 1/CU
    emb_gemm<<<grid, 256, 0, stream>>>(x, W, bias, out);
}

// Round 7
// 106.480 us; speedup vs baseline: 3.2660x; 1.1559x over previous
//
#include <hip/hip_runtime.h>

#define BATCH   16384
#define NUM_NUM 32
#define NUM_CAT 32
#define CARD    128
#define OUT_F   32
#define XSTRIDE 4128   // NUM_NUM + NUM_CAT*CARD
#define OSTRIDE 1056   // NUM_NUM + NUM_CAT*OUT_F

#define TRB    256             // rows per block
#define CK     32              // K cols per chunk -> 128B contiguous per row per stage
#define NCHUNK (CARD / CK)     // 4
#define QPC    (TRB * CK / 4)  // 2048 quads per x buffer (32 KB)

typedef const __attribute__((address_space(1))) void* as1_cvp;
typedef __attribute__((address_space(3))) void*       as3_vp;

// 256 threads = 4 waves, 2 blocks/CU (LDS 64KB). Wave wvu owns outs [wvu*8,+8):
// W addresses are wave-uniform -> s_load (SMEM pipe), W leaves the LDS pipe entirely.
// Lane l owns rows l*4+j (block-local). x_s: XOR-swizzled quads, phys P = Q^((Q>>5)&7),
// Q = row*8 + colquad (involution: XOR touches bits 0..2 only, (Q>>5)==(P>>5)).
//   read (fixed j,sq): Q = 32l+8j+sq -> xor = l&7 -> bank-quad sq^(l&7): per 16-lane
//   phase each bank-quad hit 2x -> conflict-free (r5/r6-measured pattern).
//   stage instr i (=wv*8+s): lane l -> phys P=64i+l, Q=P^((2i+(l>>5))&7): row 8i+(l>>3),
//   cq (l&7)^((2i+(l>>5))&7): 8-lane groups read one row's 128B slice (permuted in-seg).
// Epilogue: acc -> x_s[0] (swizzled, 2-way) -> read 8 lanes/row -> 128B coalesced stores.
__global__ __launch_bounds__(256, 2) void emb_gemm(const float* __restrict__ x,
                                                   const float* __restrict__ Wm,
                                                   const float* __restrict__ bias,
                                                   float* __restrict__ out) {
    __shared__ float4 x_s[2][QPC];  // 64 KB

    const int f    = blockIdx.y;
    const int row0 = blockIdx.x * TRB;
    const int tid  = threadIdx.x;
    const int l    = tid & 63;
    const int wvu  = __builtin_amdgcn_readfirstlane(tid >> 6);  // wave's out-group, SGPR
    const int lx   = l & 7;

    // Wave-uniform W quad pointer: wq[c*8] / wq[c*8+1] = W[f][c][wvu*8..+8)
    const float4* __restrict__ wq =
        (const float4*)Wm + ((size_t)f * (CARD * OUT_F / 4) + wvu * 2);

    const float* xg = x + (size_t)row0 * XSTRIDE + NUM_NUM + f * CARD;

    // per-lane inverse-swizzled staging source offsets (chunk-independent)
    int soff[8];
#pragma unroll
    for (int s = 0; s < 8; ++s) {
        int i   = wvu * 8 + s;                    // block-wide stage instr index
        int row = i * 8 + (l >> 3);
        int cq  = (l & 7) ^ ((2 * i + (l >> 5)) & 7);
        soff[s] = row * XSTRIDE + cq * 4;
    }

    // prologue: stage chunk 0 -> buf 0
#pragma unroll
    for (int s = 0; s < 8; ++s)
        __builtin_amdgcn_global_load_lds((as1_cvp)(xg + soff[s]),
                                         (as3_vp)&x_s[0][(wvu * 8 + s) * 64 + l], 16, 0, 0);
    __syncthreads();

    float acc[4][8];
#pragma unroll
    for (int j = 0; j < 4; ++j)
#pragma unroll
        for (int k = 0; k < 8; ++k) acc[j][k] = 0.0f;

    for (int ck = 0; ck < NCHUNK; ++ck) {
        if (ck + 1 < NCHUNK) {
            const float* xn  = xg + (ck + 1) * CK;
            float4*      dst = x_s[(ck + 1) & 1];
#pragma unroll
            for (int s = 0; s < 8; ++s)
                __builtin_amdgcn_global_load_lds((as1_cvp)(xn + soff[s]),
                                                 (as3_vp)&dst[(wvu * 8 + s) * 64 + l], 16, 0, 0);
        }

        const float4* xb = x_s[ck & 1];
#pragma unroll
        for (int sq = 0; sq < 8; ++sq) {
            float4 xv[4];
#pragma unroll
            for (int j = 0; j < 4; ++j) {
                int Q = 32 * l + 8 * j + sq;
                xv[j] = xb[Q ^ lx];
            }
#pragma unroll
            for (int cc = 0; cc < 4; ++cc) {
                const int    c  = ck * CK + sq * 4 + cc;
                const float4 wa = wq[c * 8];      // scalar loads (uniform address)
                const float4 wb = wq[c * 8 + 1];
#pragma unroll
                for (int j = 0; j < 4; ++j) {
                    const float xf = (&xv[j].x)[cc];
                    float*      a  = acc[j];
                    a[0] += xf * wa.x;  a[1] += xf * wa.y;
                    a[2] += xf * wa.z;  a[3] += xf * wa.w;
                    a[4] += xf * wb.x;  a[5] += xf * wb.y;
                    a[6] += xf * wb.z;  a[7] += xf * wb.w;
                }
            }
        }
        __syncthreads();  // publishes staged chunk ck+1; buf ck free for iter ck+2
    }

    // ---- epilogue: transpose through x_s[0] for coalesced stores ----
#pragma unroll
    for (int j = 0; j < 4; ++j)
#pragma unroll
        for (int k = 0; k < 2; ++k) {
            int Qw = 32 * l + 8 * j + wvu * 2 + k;  // row = l*4+j, colquad = wvu*2+k
            x_s[0][Qw ^ lx] =
                make_float4(acc[j][k * 4], acc[j][k * 4 + 1], acc[j][k * 4 + 2], acc[j][k * 4 + 3]);
        }
    __syncthreads();

    const int    og8  = tid & 7;    // 8 lanes cover one row's 32 cols = 128B
    const int    rg32 = tid >> 3;   // 32 rows per pass
    const float4 bq   = ((const float4*)bias)[f * 8 + og8];
#pragma unroll
    for (int p = 0; p < 8; ++p) {
        int    Qr = 256 * p + 8 * rg32 + og8;
        float4 v  = x_s[0][Qr ^ (rg32 >> 2)];
        v.x += bq.x; v.y += bq.y; v.z += bq.z; v.w += bq.w;
        int row = row0 + p * 32 + rg32;
        *(float4*)(out + (size_t)row * OSTRIDE + NUM_NUM + f * OUT_F + og8 * 4) = v;
    }

    // ---- numeric passthrough, distributed: block (rb,f) copies rows [row0+f*8, +8) ----
    if (tid < 64) {
        int r  = row0 + f * 8 + (tid >> 3);
        int c4 = (tid & 7) << 2;
        *(float4*)(out + (size_t)r * OSTRIDE + c4) =
            *(const float4*)(x + (size_t)r * XSTRIDE + c4);
    }
}

extern "C" void kernel_launch(void* const* d_in, const int* in_sizes, int n_in,
                              void* d_out, int out_size, void* d_ws, size_t ws_size,
                              hipStream_t stream) {
    const float* x    = (const float*)d_in[0];
    const float* W    = (const float*)d_in[1];
    const float* bias = (const float*)d_in[2];
    float*       out  = (float*)d_out;

    dim3 grid(BATCH / TRB, NUM_CAT);  // 64 x 32 = 2048 blocks, 2/CU
    emb_gemm<<<grid, 256, 0, stream>>>(x, W, bias, out);
}